// Round 11
// baseline (16541.785 us; speedup 1.0000x reference)
//
#include <hip/hip_runtime.h>
#include <stdint.h>

#define L_SEQ 4096
#define E_DIM 512
#define H_DIM 512
#define G_DIM 2048   // 4*H
#define NTAG  32
#define RING_SLOTS 4  // all-to-all wait each step -> skew <= 1; 4 is generous

typedef unsigned long long u64;
typedef unsigned short     u16;
typedef unsigned char      u8;

__device__ __forceinline__ float bf2f(u16 u) {
    union { unsigned int i; float f; } v; v.i = ((unsigned int)u) << 16; return v.f;
}
// dtype sniff: trans[START][0..1] both exactly -10000.0.
// bf16: u16[0]==u16[1]==0xC61C. f32 (bits 0xC61C4000): u16[0]=0x4000 != u16[1].
__device__ __forceinline__ bool sniff_f32(const void* trans_raw) {
    const u16* p = (const u16*)trans_raw;
    return p[0] != p[1];
}
__device__ __forceinline__ float ldf(const void* base, long idx, bool isf32) {
    if (isf32) return ((const float*)base)[idx];
    return bf2f(((const u16*)base)[idx]);
}
__device__ __forceinline__ void unpack8_bf16(const u16* src, float* dst) {
    uint4 p = *(const uint4*)src;
    dst[0] = __uint_as_float(p.x << 16); dst[1] = __uint_as_float(p.x & 0xffff0000u);
    dst[2] = __uint_as_float(p.y << 16); dst[3] = __uint_as_float(p.y & 0xffff0000u);
    dst[4] = __uint_as_float(p.z << 16); dst[5] = __uint_as_float(p.z & 0xffff0000u);
    dst[6] = __uint_as_float(p.w << 16); dst[7] = __uint_as_float(p.w & 0xffff0000u);
}

// fast activations: v_exp_f32 (2^x) + v_rcp_f32. Saturate cleanly at +-inf.
#define LOG2E 1.44269504088896340736f
__device__ __forceinline__ float fsig(float x) {
    return __builtin_amdgcn_rcpf(1.f + __builtin_amdgcn_exp2f(-x * LOG2E));
}
__device__ __forceinline__ float ftanh(float x) {
    return 1.f - 2.f * __builtin_amdgcn_rcpf(1.f + __builtin_amdgcn_exp2f(x * (2.f * LOG2E)));
}

// ---------------------------------------------------------------------------
// K1: xp = gather(embed,sent) @ w_ih^T + (b_ih+b_hh). Grid (128, 2).
// r10: 2x2 register tiling — 32m x 32g tiles (132 KB LDS, 1 WG/CU), each
// thread computes (mi,mi+16)x(gi,gi+16): 4 ds_read_b128 feed 16 FMAs
// = 1 B/FLOP (4x less LDS traffic than the 1x1 version).
// Also bumps the per-run tag salt for the k_lstm exchange ring.
// ---------------------------------------------------------------------------
__global__ __launch_bounds__(256) void k_xproj(
    const int* __restrict__ sent, const void* __restrict__ embed,
    const void* __restrict__ w_ih_f, const void* __restrict__ b_ih_f, const void* __restrict__ b_hh_f,
    const void* __restrict__ w_ih_b, const void* __restrict__ b_ih_b, const void* __restrict__ b_hh_b,
    const void* __restrict__ trans_raw,
    float* __restrict__ xp_f, float* __restrict__ xp_b,
    int* __restrict__ ctrl)
{
    if (blockIdx.x == 0 && blockIdx.y == 0 && threadIdx.x == 0) {
        ctrl[4] = ctrl[4] + 8192;   // per-run tag salt (> max step tag 4096)
    }
    const bool isf32 = sniff_f32(trans_raw);
    const int dir = (int)blockIdx.y;
    const void* W  = dir ? w_ih_b : w_ih_f;
    const void* bi = dir ? b_ih_b : b_ih_f;
    const void* bh = dir ? b_hh_b : b_hh_f;
    float* xp = dir ? xp_b : xp_f;
    const int m0 = (int)blockIdx.x * 32;
    const int tid = (int)threadIdx.x;

    __shared__ float xs[32][516];   // 66 KB
    __shared__ float wl[32][516];   // 66 KB  (total 132 KB -> 1 WG/CU)

    {   // stage xs: 32 rows x 512; each thread loads 64 contiguous elems
        const int r = tid >> 3, c0 = (tid & 7) * 64;
        const long row = sent[m0 + r];
        if (isf32) {
            const float* src = (const float*)embed + row * E_DIM + c0;
            #pragma unroll
            for (int i = 0; i < 64; i += 4) *(float4*)&xs[r][c0 + i] = *(const float4*)(src + i);
        } else {
            const u16* src = (const u16*)embed + row * E_DIM + c0;
            #pragma unroll
            for (int i = 0; i < 64; i += 8) unpack8_bf16(src + i, &xs[r][c0 + i]);
        }
    }
    __syncthreads();

    const int gi = tid & 15, mi = tid >> 4;   // 16 x 16 thread grid
    for (int gb = 0; gb < 64; ++gb) {
        const int g0 = gb * 32;
        {   // stage wl: 32 rows x 512
            const int r = tid >> 3, c0 = (tid & 7) * 64;
            if (isf32) {
                const float* src = (const float*)W + (long)(g0 + r) * E_DIM + c0;
                #pragma unroll
                for (int i = 0; i < 64; i += 4) *(float4*)&wl[r][c0 + i] = *(const float4*)(src + i);
            } else {
                const u16* src = (const u16*)W + (long)(g0 + r) * E_DIM + c0;
                #pragma unroll
                for (int i = 0; i < 64; i += 8) unpack8_bf16(src + i, &wl[r][c0 + i]);
            }
        }
        __syncthreads();

        float a00 = 0.f, a01 = 0.f, a10 = 0.f, a11 = 0.f;
        #pragma unroll 4
        for (int k = 0; k < E_DIM; k += 4) {
            const float4 xa = *(const float4*)&xs[mi][k];
            const float4 xb = *(const float4*)&xs[mi + 16][k];
            const float4 wa = *(const float4*)&wl[gi][k];
            const float4 wb = *(const float4*)&wl[gi + 16][k];
            a00 = fmaf(xa.x, wa.x, a00); a00 = fmaf(xa.y, wa.y, a00);
            a00 = fmaf(xa.z, wa.z, a00); a00 = fmaf(xa.w, wa.w, a00);
            a01 = fmaf(xa.x, wb.x, a01); a01 = fmaf(xa.y, wb.y, a01);
            a01 = fmaf(xa.z, wb.z, a01); a01 = fmaf(xa.w, wb.w, a01);
            a10 = fmaf(xb.x, wa.x, a10); a10 = fmaf(xb.y, wa.y, a10);
            a10 = fmaf(xb.z, wa.z, a10); a10 = fmaf(xb.w, wa.w, a10);
            a11 = fmaf(xb.x, wb.x, a11); a11 = fmaf(xb.y, wb.y, a11);
            a11 = fmaf(xb.z, wb.z, a11); a11 = fmaf(xb.w, wb.w, a11);
        }
        const int g  = g0 + gi;
        const int g2 = g0 + gi + 16;
        const float bg  = ldf(bi, g,  isf32) + ldf(bh, g,  isf32);
        const float bg2 = ldf(bi, g2, isf32) + ldf(bh, g2, isf32);
        xp[(long)(m0 + mi)      * G_DIM + g ] = a00 + bg;
        xp[(long)(m0 + mi)      * G_DIM + g2] = a01 + bg2;
        xp[(long)(m0 + mi + 16) * G_DIM + g ] = a10 + bg;
        xp[(long)(m0 + mi + 16) * G_DIM + g2] = a11 + bg2;
        __syncthreads();
    }
}

// ---------------------------------------------------------------------------
// K2: persistent BiLSTM, 64 WGs (32/dir), 16 h-dims per WG — r9's proven
// kernel, byte-identical (best measured: 8.33 ms). Far-atomic (atomicExch)
// publish + agent-load poll on a 16 KB 4-slot tagged ring. Exchange protocol
// family is closed: 7 HW-tested variants; step floor ~4.9 kcy (fabric
// visibility latency of the serial cross-CU recurrence).
// ---------------------------------------------------------------------------
__global__ __launch_bounds__(256, 1) void k_lstm(
    const void* __restrict__ w_hh_f, const void* __restrict__ w_hh_b,
    const void* __restrict__ h0, const void* __restrict__ c0,
    const void* __restrict__ trans_raw,
    const float* __restrict__ xp_f, const float* __restrict__ xp_b,
    float* __restrict__ hs_f, float* __restrict__ hs_b,
    u64* __restrict__ ring_f, u64* __restrict__ ring_b,
    const int* __restrict__ ctrl)
{
    const bool isf32 = sniff_f32(trans_raw);
    const int dir = (int)(blockIdx.x >> 5);
    const int wg  = (int)(blockIdx.x & 31);
    const int j0  = wg * 16;
    const unsigned salt = (unsigned)ctrl[4];
    const void* Whh = dir ? w_hh_b : w_hh_f;
    const float* xp = dir ? xp_b : xp_f;
    float* hs       = dir ? hs_b : hs_f;
    u64* ring       = dir ? ring_b : ring_f;

    const int tid = (int)threadIdx.x;
    const int rp  = tid >> 3;      // row-pair 0..31
    const int ks  = tid & 7;       // k-segment (64 wide)
    const int d   = rp >> 1;       // local dim 0..15
    const int gp  = rp & 1;        // 0 -> gates i,f ; 1 -> gates g,o
    const int g0r = gp * 2;

    __shared__ float h_lds[512 + 32];   // p(j) = j + ((j>>6)<<2)

    // 2 rows x 64 k of W_hh per lane (f32 in VGPRs; 128 total -> no spill)
    float wreg[2][64];
    #pragma unroll
    for (int rl = 0; rl < 2; ++rl) {
        const long roff = (long)((g0r + rl) * H_DIM + j0 + d) * H_DIM + ks * 64;
        if (isf32) {
            const float* wrow = (const float*)Whh + roff;
            #pragma unroll
            for (int b = 0; b < 16; ++b) *(float4*)&wreg[rl][b * 4] = *(const float4*)(wrow + b * 4);
        } else {
            const u16* wrow = (const u16*)Whh + roff;
            #pragma unroll
            for (int b = 0; b < 8; ++b) unpack8_bf16(wrow + b * 8, &wreg[rl][b * 8]);
        }
    }

    {   // init h_lds (w0 even: never straddles a 64-block)
        const int w0 = tid * 2;
        h_lds[w0 + ((w0 >> 6) << 2)]     = ldf(h0, dir * H_DIM + w0, isf32);
        h_lds[w0 + 1 + ((w0 >> 6) << 2)] = ldf(h0, dir * H_DIM + w0 + 1, isf32);
    }

    const bool is_act = ((tid & 15) == 0);   // ks==0 && gp==0: one per dim
    const int  jown   = j0 + d;
    float cst = 0.f;
    if (is_act) cst = ldf(c0, dir * H_DIM + jown, isf32);

    // poller mapping: 240 non-act lanes cover 496 remote words (2 or 3 each)
    const int b16 = tid >> 4, off = tid & 15;
    const int pidx = is_act ? -1 : (b16 * 15 + off - 1);   // 0..239
    int jw0 = 0, jw1 = 0, jw2 = -1;
    if (pidx >= 0) {
        const int w0 = 2 * pidx, w1 = 2 * pidx + 1;
        jw0 = w0 + (w0 >= j0 ? 16 : 0);
        jw1 = w1 + (w1 >= j0 ? 16 : 0);
        if (pidx < 16) { const int w2 = 480 + pidx; jw2 = w2 + (w2 >= j0 ? 16 : 0); }
    }

    int t = dir ? (L_SEQ - 1) : 0;
    float xc0 = 0, xc1 = 0, xc2 = 0, xc3 = 0, xn0 = 0, xn1 = 0, xn2 = 0, xn3 = 0;
    if (is_act) {
        const float* xr = xp + (long)t * G_DIM + jown;
        xn0 = xr[0]; xn1 = xr[H_DIM]; xn2 = xr[2 * H_DIM]; xn3 = xr[3 * H_DIM];
    }
    __syncthreads();

    #pragma unroll 1
    for (int k = 0; k < L_SEQ; ++k) {
        t = dir ? (L_SEQ - 1 - k) : k;
        const long rb = (long)(k & (RING_SLOTS - 1)) * H_DIM;
        const unsigned tagv = salt + (unsigned)(k + 1);

        if (is_act) {
            xc0 = xn0; xc1 = xn1; xc2 = xn2; xc3 = xn3;
            if (k + 1 < L_SEQ) {
                const int nt = dir ? (t - 1) : (t + 1);
                const float* xr = xp + (long)nt * G_DIM + jown;
                xn0 = xr[0]; xn1 = xr[H_DIM]; xn2 = xr[2 * H_DIM]; xn3 = xr[3 * H_DIM];
            }
        }

        // matvec: 2 rows x 64 k (16 ds_read_b128, conflict-free via 68-stride)
        float a0 = 0, a1 = 0;
        const float4* hb = (const float4*)(h_lds + ks * 68);
        #pragma unroll
        for (int q = 0; q < 16; ++q) {
            const float4 hv = hb[q];
            a0 = fmaf(wreg[0][4*q+0], hv.x, a0); a0 = fmaf(wreg[0][4*q+1], hv.y, a0);
            a0 = fmaf(wreg[0][4*q+2], hv.z, a0); a0 = fmaf(wreg[0][4*q+3], hv.w, a0);
            a1 = fmaf(wreg[1][4*q+0], hv.x, a1); a1 = fmaf(wreg[1][4*q+1], hv.y, a1);
            a1 = fmaf(wreg[1][4*q+2], hv.z, a1); a1 = fmaf(wreg[1][4*q+3], hv.w, a1);
        }
        // k-reduce across the 8 ks lanes (tid bits 0..2 -> in-wave)
        #pragma unroll
        for (int m = 1; m < 8; m <<= 1) { a0 += __shfl_xor(a0, m); a1 += __shfl_xor(a1, m); }
        // partner row-pair (tid bit 3): other two gates of the same dim
        const float b0 = __shfl_xor(a0, 8);
        const float b1 = __shfl_xor(a1, 8);

        if (is_act) {
            const float iv = fsig(a0 + xc0);     // gate i (row g=0)
            const float fo = fsig(a1 + xc1);     // gate f (row g=1)
            const float gv = ftanh(b0 + xc2);    // gate g (row g=2, partner)
            const float ov = fsig(b1 + xc3);     // gate o (row g=3, partner)
            cst = fo * cst + iv * gv;
            const float hv2 = ov * ftanh(cst);
            h_lds[jown + ((jown >> 6) << 2)] = hv2;
            hs[(long)t * H_DIM + jown] = hv2;                 // history for k_feats
            const u64 pk = (((u64)tagv) << 32) | (u64)__float_as_uint(hv2);
            // far-atomic publish: RMW executes at the device coherence point.
            atomicExch(&ring[rb + jown], pk);
        }

        if (k + 1 < L_SEQ && pidx >= 0) {
            u64* pa0 = &ring[rb + jw0];
            u64* pa1 = &ring[rb + jw1];
            u64* pa2 = (jw2 >= 0) ? &ring[rb + jw2] : pa0;
            u64 v0 = 0, v1 = 0, v2 = 0;
            bool q0 = false, q1 = false, q2 = (jw2 < 0);
            do {   // all missing words polled concurrently -> 1-latency retry period
                if (!q0) { v0 = __hip_atomic_load(pa0, __ATOMIC_RELAXED, __HIP_MEMORY_SCOPE_AGENT); }
                if (!q1) { v1 = __hip_atomic_load(pa1, __ATOMIC_RELAXED, __HIP_MEMORY_SCOPE_AGENT); }
                if (!q2) { v2 = __hip_atomic_load(pa2, __ATOMIC_RELAXED, __HIP_MEMORY_SCOPE_AGENT); }
                q0 = q0 || ((unsigned)(v0 >> 32) == tagv);
                q1 = q1 || ((unsigned)(v1 >> 32) == tagv);
                q2 = q2 || ((unsigned)(v2 >> 32) == tagv);
            } while (!(q0 && q1 && q2));
            h_lds[jw0 + ((jw0 >> 6) << 2)] = __uint_as_float((unsigned)v0);
            h_lds[jw1 + ((jw1 >> 6) << 2)] = __uint_as_float((unsigned)v1);
            if (jw2 >= 0) h_lds[jw2 + ((jw2 >> 6) << 2)] = __uint_as_float((unsigned)v2);
        }
        __syncthreads();
    }
}

// ---------------------------------------------------------------------------
// K3: feats[t][n] = hs_f[t]·w_out[n][:512] + hs_b[t]·w_out[n][512:] + b_out[n]
// ---------------------------------------------------------------------------
__global__ __launch_bounds__(256) void k_feats(
    const float* __restrict__ hs_f, const float* __restrict__ hs_b,
    const void* __restrict__ w_out, const void* __restrict__ b_out,
    const void* __restrict__ trans_raw, float* __restrict__ feats)
{
    const bool isf32 = sniff_f32(trans_raw);
    const int n  = (int)threadIdx.x & 31;
    const int tl = (int)threadIdx.x >> 5;
    const int t  = (int)blockIdx.x * 8 + tl;
    const float* hf = hs_f + (long)t * H_DIM;
    const float* hb = hs_b + (long)t * H_DIM;
    float acc = ldf(b_out, n, isf32);
    if (isf32) {
        const float* wf = (const float*)w_out + (long)n * 1024;
        const float* wb = wf + 512;
        #pragma unroll 4
        for (int j = 0; j < 512; j += 4) {
            const float4 hv = *(const float4*)&hf[j];
            const float4 wv = *(const float4*)&wf[j];
            acc = fmaf(hv.x, wv.x, acc); acc = fmaf(hv.y, wv.y, acc);
            acc = fmaf(hv.z, wv.z, acc); acc = fmaf(hv.w, wv.w, acc);
            const float4 hv2 = *(const float4*)&hb[j];
            const float4 wv2 = *(const float4*)&wb[j];
            acc = fmaf(hv2.x, wv2.x, acc); acc = fmaf(hv2.y, wv2.y, acc);
            acc = fmaf(hv2.z, wv2.z, acc); acc = fmaf(hv2.w, wv2.w, acc);
        }
    } else {
        const u16* wfh = (const u16*)w_out + (long)n * 1024;
        const u16* wbh = wfh + 512;
        #pragma unroll 2
        for (int j = 0; j < 512; j += 8) {
            float wt[8];
            unpack8_bf16(&wfh[j], wt);
            const float4 h0v = *(const float4*)&hf[j];
            const float4 h1v = *(const float4*)&hf[j + 4];
            acc = fmaf(h0v.x, wt[0], acc); acc = fmaf(h0v.y, wt[1], acc);
            acc = fmaf(h0v.z, wt[2], acc); acc = fmaf(h0v.w, wt[3], acc);
            acc = fmaf(h1v.x, wt[4], acc); acc = fmaf(h1v.y, wt[5], acc);
            acc = fmaf(h1v.z, wt[6], acc); acc = fmaf(h1v.w, wt[7], acc);
            unpack8_bf16(&wbh[j], wt);
            const float4 h2v = *(const float4*)&hb[j];
            const float4 h3v = *(const float4*)&hb[j + 4];
            acc = fmaf(h2v.x, wt[0], acc); acc = fmaf(h2v.y, wt[1], acc);
            acc = fmaf(h2v.z, wt[2], acc); acc = fmaf(h2v.w, wt[3], acc);
            acc = fmaf(h3v.x, wt[4], acc); acc = fmaf(h3v.y, wt[5], acc);
            acc = fmaf(h3v.z, wt[6], acc); acc = fmaf(h3v.w, wt[7], acc);
        }
    }
    feats[(long)t * 32 + n] = acc;
}

// ---------------------------------------------------------------------------
// K4: Viterbi forward. NEW (r11): shuffle-free in-lane argmax. Each lane
// holds the FULL trans row for its state n (tr[32], regs) and broadcast-
// reads ALL 32 fv values (8 x ds_read_b128, one batched wait). Leftmost-max
// tree (combine = a.v >= b.v ? a : b, left earlier) == reference first-max
// under strict >; fp max is exactly associative so the score is bit-exact.
// Removes both serial __shfl_xor(32) (~240 cy) and the 16-deep dependent
// compare chain from the per-step critical path. Single wave, no barriers.
// Then chunked parallel backtrace (unchanged).
// Output (f32): out[0]=score, out[1..]=path.
// ---------------------------------------------------------------------------
__global__ __launch_bounds__(64) void k_viterbi(
    const float* __restrict__ feats, const void* __restrict__ trans_raw,
    u8* __restrict__ bptr, float* __restrict__ out)
{
    const bool isf32 = sniff_f32(trans_raw);
    const int lane = (int)threadIdx.x;
    const int n = lane & 31, half = lane >> 5;
    __shared__ __align__(16) float fv_l[32];
    __shared__ u8 mlds[64 * 32];
    __shared__ u8 entry[64];

    float tr[32];
    #pragma unroll
    for (int i = 0; i < 32; ++i) tr[i] = ldf(trans_raw, n * 32 + i, isf32);
    const float tr_end = ldf(trans_raw, 32 + n, isf32);   // trans[END=1][n]

    if (half == 0) fv_l[n] = (n == 0) ? 0.f : -10000.f;   // START=0
    float fvreg = 0.f;
    float fnext = feats[n];
    #pragma unroll 1
    for (int tt = 0; tt < L_SEQ; ++tt) {
        const float fcur = fnext;
        const int nt = (tt + 1 < L_SEQ) ? tt + 1 : tt;
        fnext = feats[(long)nt * 32 + n];

        // broadcast-read all 32 fv values (8 x ds_read_b128, batched)
        float fvv[32];
        #pragma unroll
        for (int q = 0; q < 8; ++q)
            *(float4*)&fvv[q * 4] = *(const float4*)&fv_l[q * 4];

        // leftmost-max tree over c_i = tr[i] + fvv[i] (no cross-lane ops)
        float bv[16]; int bx[16];
        #pragma unroll
        for (int i = 0; i < 16; ++i) {
            const float c0 = tr[2 * i]     + fvv[2 * i];
            const float c1 = tr[2 * i + 1] + fvv[2 * i + 1];
            const bool w = (c0 >= c1);
            bv[i] = w ? c0 : c1; bx[i] = w ? 2 * i : 2 * i + 1;
        }
        #pragma unroll
        for (int s = 8; s >= 1; s >>= 1) {
            #pragma unroll
            for (int i = 0; i < 8; ++i) {
                if (i < s) {
                    const bool w = (bv[2 * i] >= bv[2 * i + 1]);
                    bv[i] = w ? bv[2 * i] : bv[2 * i + 1];
                    bx[i] = w ? bx[2 * i] : bx[2 * i + 1];
                }
            }
        }
        const float best = bv[0]; const int bp = bx[0];

        fvreg = best + fcur;                   // lanes n and n+32 identical
        if (half == 0) {
            bptr[(long)tt * 32 + n] = (u8)bp;
            fv_l[n] = fvreg;                   // publish fv(t+1); in-wave, in-order LDS
        }
    }

    float term = (half == 0) ? (fvreg + tr_end) : -3.4e38f;
    int   ti   = (half == 0) ? n : 1000;
    #pragma unroll
    for (int m = 1; m < 64; m <<= 1) {
        const float ov = __shfl_xor(term, m);
        const int   oi = __shfl_xor(ti, m);
        if (ov > term || (ov == term && oi < ti)) { term = ov; ti = oi; }
    }
    if (lane == 0) out[0] = term;
    __syncthreads();

    unsigned cur[32];
    #pragma unroll
    for (int ch = 0; ch < 32; ++ch) cur[ch] = (unsigned)ch;
    const int cbase = lane * 64;
    for (int s = 63; s >= 0; --s) {
        const u8* row = bptr + (long)(cbase + s) * 32;
        #pragma unroll
        for (int ch = 0; ch < 32; ++ch) cur[ch] = row[cur[ch]];
    }
    #pragma unroll
    for (int ch = 0; ch < 32; ++ch) mlds[lane * 32 + ch] = (u8)cur[ch];
    __syncthreads();

    if (lane == 0) {
        int tag = ti;
        for (int c = 63; c >= 0; --c) { entry[c] = (u8)tag; tag = mlds[c * 32 + tag]; }
    }
    __syncthreads();

    {
        int tag = entry[lane];
        for (int s = 63; s >= 0; --s) {
            const int gidx = cbase + s;
            out[1 + gidx] = (float)tag;
            tag = bptr[(long)gidx * 32 + tag];
        }
    }
}

// ---------------------------------------------------------------------------
extern "C" void kernel_launch(void* const* d_in, const int* in_sizes, int n_in,
                              void* d_out, int out_size, void* d_ws, size_t ws_size,
                              hipStream_t stream)
{
    (void)in_sizes; (void)n_in; (void)out_size; (void)ws_size;
    const int* sent  = (const int*)d_in[0];
    const void* embed  = d_in[1];
    const void* w_ih_f = d_in[2];
    const void* w_hh_f = d_in[3];
    const void* b_ih_f = d_in[4];
    const void* b_hh_f = d_in[5];
    const void* w_ih_b = d_in[6];
    const void* w_hh_b = d_in[7];
    const void* b_ih_b = d_in[8];
    const void* b_hh_b = d_in[9];
    const void* w_out  = d_in[10];
    const void* b_out  = d_in[11];
    const void* h0     = d_in[12];
    const void* c0     = d_in[13];
    const void* trans  = d_in[14];

    // Layout: 80.2 MB total, within the baseline's proven 96 MB footprint.
    char* ws = (char*)d_ws;
    float* xp_f  = (float*)(ws);                              // 32 MB
    float* xp_b  = (float*)(ws + (32ull << 20));              // 32 MB
    float* hs_f  = (float*)(ws + (64ull << 20));              //  8 MB (4096x512 f32)
    float* hs_b  = (float*)(ws + (72ull << 20));              //  8 MB
    u64*   ring_f = (u64*)(ws + (80ull << 20));               // 16 KB (4x512 u64)
    u64*   ring_b = (u64*)(ws + (80ull << 20) + (64u << 10)); // 16 KB
    int*   ctrl   = (int*)(ws + (80ull << 20) + (128u << 10));// 32 B (salt)
    float* feats = (float*)(ws);                              // reuses xp_f (dead)
    u8*    bptr  = (u8*)(ws + (1ull << 20));                  // 128 KB, dead region

    k_xproj<<<dim3(128, 2), 256, 0, stream>>>(sent, embed,
        w_ih_f, b_ih_f, b_hh_f, w_ih_b, b_ih_b, b_hh_b, trans, xp_f, xp_b, ctrl);
    k_lstm<<<64, 256, 0, stream>>>(w_hh_f, w_hh_b, h0, c0, trans, xp_f, xp_b,
                                   hs_f, hs_b, ring_f, ring_b, ctrl);
    k_feats<<<512, 256, 0, stream>>>(hs_f, hs_b, w_out, b_out, trans, feats);
    k_viterbi<<<1, 64, 0, stream>>>(feats, trans, bptr, (float*)d_out);
}

// Round 12
// 10846.278 us; speedup vs baseline: 1.5251x; 1.5251x over previous
//
#include <hip/hip_runtime.h>
#include <stdint.h>

#define L_SEQ 4096
#define E_DIM 512
#define H_DIM 512
#define G_DIM 2048   // 4*H
#define NTAG  32
#define RING_SLOTS 4  // all-to-all wait each step -> skew <= 1; 4 is generous

typedef unsigned long long u64;
typedef unsigned short     u16;
typedef unsigned char      u8;

__device__ __forceinline__ float bf2f(u16 u) {
    union { unsigned int i; float f; } v; v.i = ((unsigned int)u) << 16; return v.f;
}
// dtype sniff: trans[START][0..1] both exactly -10000.0.
// bf16: u16[0]==u16[1]==0xC61C. f32 (bits 0xC61C4000): u16[0]=0x4000 != u16[1].
__device__ __forceinline__ bool sniff_f32(const void* trans_raw) {
    const u16* p = (const u16*)trans_raw;
    return p[0] != p[1];
}
__device__ __forceinline__ float ldf(const void* base, long idx, bool isf32) {
    if (isf32) return ((const float*)base)[idx];
    return bf2f(((const u16*)base)[idx]);
}
__device__ __forceinline__ void unpack8_bf16(const u16* src, float* dst) {
    uint4 p = *(const uint4*)src;
    dst[0] = __uint_as_float(p.x << 16); dst[1] = __uint_as_float(p.x & 0xffff0000u);
    dst[2] = __uint_as_float(p.y << 16); dst[3] = __uint_as_float(p.y & 0xffff0000u);
    dst[4] = __uint_as_float(p.z << 16); dst[5] = __uint_as_float(p.z & 0xffff0000u);
    dst[6] = __uint_as_float(p.w << 16); dst[7] = __uint_as_float(p.w & 0xffff0000u);
}

// fast activations: v_exp_f32 (2^x) + v_rcp_f32. Saturate cleanly at +-inf.
#define LOG2E 1.44269504088896340736f
__device__ __forceinline__ float fsig(float x) {
    return __builtin_amdgcn_rcpf(1.f + __builtin_amdgcn_exp2f(-x * LOG2E));
}
__device__ __forceinline__ float ftanh(float x) {
    return 1.f - 2.f * __builtin_amdgcn_rcpf(1.f + __builtin_amdgcn_exp2f(x * (2.f * LOG2E)));
}

// ---------------------------------------------------------------------------
// K1: xp = gather(embed,sent) @ w_ih^T + (b_ih+b_hh). Grid (128, 2).
// r10: 2x2 register tiling — 32m x 32g tiles (132 KB LDS, 1 WG/CU), each
// thread computes (mi,mi+16)x(gi,gi+16): 4 ds_read_b128 feed 16 FMAs
// = 1 B/FLOP (4x less LDS traffic than the 1x1 version).
// Also bumps the per-run tag salt for the k_lstm exchange ring.
// ---------------------------------------------------------------------------
__global__ __launch_bounds__(256) void k_xproj(
    const int* __restrict__ sent, const void* __restrict__ embed,
    const void* __restrict__ w_ih_f, const void* __restrict__ b_ih_f, const void* __restrict__ b_hh_f,
    const void* __restrict__ w_ih_b, const void* __restrict__ b_ih_b, const void* __restrict__ b_hh_b,
    const void* __restrict__ trans_raw,
    float* __restrict__ xp_f, float* __restrict__ xp_b,
    int* __restrict__ ctrl)
{
    if (blockIdx.x == 0 && blockIdx.y == 0 && threadIdx.x == 0) {
        ctrl[4] = ctrl[4] + 8192;   // per-run tag salt (> max step tag 4096)
    }
    const bool isf32 = sniff_f32(trans_raw);
    const int dir = (int)blockIdx.y;
    const void* W  = dir ? w_ih_b : w_ih_f;
    const void* bi = dir ? b_ih_b : b_ih_f;
    const void* bh = dir ? b_hh_b : b_hh_f;
    float* xp = dir ? xp_b : xp_f;
    const int m0 = (int)blockIdx.x * 32;
    const int tid = (int)threadIdx.x;

    __shared__ float xs[32][516];   // 66 KB
    __shared__ float wl[32][516];   // 66 KB  (total 132 KB -> 1 WG/CU)

    {   // stage xs: 32 rows x 512; each thread loads 64 contiguous elems
        const int r = tid >> 3, c0 = (tid & 7) * 64;
        const long row = sent[m0 + r];
        if (isf32) {
            const float* src = (const float*)embed + row * E_DIM + c0;
            #pragma unroll
            for (int i = 0; i < 64; i += 4) *(float4*)&xs[r][c0 + i] = *(const float4*)(src + i);
        } else {
            const u16* src = (const u16*)embed + row * E_DIM + c0;
            #pragma unroll
            for (int i = 0; i < 64; i += 8) unpack8_bf16(src + i, &xs[r][c0 + i]);
        }
    }
    __syncthreads();

    const int gi = tid & 15, mi = tid >> 4;   // 16 x 16 thread grid
    for (int gb = 0; gb < 64; ++gb) {
        const int g0 = gb * 32;
        {   // stage wl: 32 rows x 512
            const int r = tid >> 3, c0 = (tid & 7) * 64;
            if (isf32) {
                const float* src = (const float*)W + (long)(g0 + r) * E_DIM + c0;
                #pragma unroll
                for (int i = 0; i < 64; i += 4) *(float4*)&wl[r][c0 + i] = *(const float4*)(src + i);
            } else {
                const u16* src = (const u16*)W + (long)(g0 + r) * E_DIM + c0;
                #pragma unroll
                for (int i = 0; i < 64; i += 8) unpack8_bf16(src + i, &wl[r][c0 + i]);
            }
        }
        __syncthreads();

        float a00 = 0.f, a01 = 0.f, a10 = 0.f, a11 = 0.f;
        #pragma unroll 4
        for (int k = 0; k < E_DIM; k += 4) {
            const float4 xa = *(const float4*)&xs[mi][k];
            const float4 xb = *(const float4*)&xs[mi + 16][k];
            const float4 wa = *(const float4*)&wl[gi][k];
            const float4 wb = *(const float4*)&wl[gi + 16][k];
            a00 = fmaf(xa.x, wa.x, a00); a00 = fmaf(xa.y, wa.y, a00);
            a00 = fmaf(xa.z, wa.z, a00); a00 = fmaf(xa.w, wa.w, a00);
            a01 = fmaf(xa.x, wb.x, a01); a01 = fmaf(xa.y, wb.y, a01);
            a01 = fmaf(xa.z, wb.z, a01); a01 = fmaf(xa.w, wb.w, a01);
            a10 = fmaf(xb.x, wa.x, a10); a10 = fmaf(xb.y, wa.y, a10);
            a10 = fmaf(xb.z, wa.z, a10); a10 = fmaf(xb.w, wa.w, a10);
            a11 = fmaf(xb.x, wb.x, a11); a11 = fmaf(xb.y, wb.y, a11);
            a11 = fmaf(xb.z, wb.z, a11); a11 = fmaf(xb.w, wb.w, a11);
        }
        const int g  = g0 + gi;
        const int g2 = g0 + gi + 16;
        const float bg  = ldf(bi, g,  isf32) + ldf(bh, g,  isf32);
        const float bg2 = ldf(bi, g2, isf32) + ldf(bh, g2, isf32);
        xp[(long)(m0 + mi)      * G_DIM + g ] = a00 + bg;
        xp[(long)(m0 + mi)      * G_DIM + g2] = a01 + bg2;
        xp[(long)(m0 + mi + 16) * G_DIM + g ] = a10 + bg;
        xp[(long)(m0 + mi + 16) * G_DIM + g2] = a11 + bg2;
        __syncthreads();
    }
}

// ---------------------------------------------------------------------------
// K2: persistent BiLSTM, 64 WGs (32/dir), 16 h-dims per WG — r9's proven
// kernel, byte-identical (best measured: 8.33 ms). Far-atomic (atomicExch)
// publish + agent-load poll on a 16 KB 4-slot tagged ring. Exchange protocol
// family is closed: 7 HW-tested variants; step floor ~4.9 kcy (fabric
// visibility latency of the serial cross-CU recurrence).
// ---------------------------------------------------------------------------
__global__ __launch_bounds__(256, 1) void k_lstm(
    const void* __restrict__ w_hh_f, const void* __restrict__ w_hh_b,
    const void* __restrict__ h0, const void* __restrict__ c0,
    const void* __restrict__ trans_raw,
    const float* __restrict__ xp_f, const float* __restrict__ xp_b,
    float* __restrict__ hs_f, float* __restrict__ hs_b,
    u64* __restrict__ ring_f, u64* __restrict__ ring_b,
    const int* __restrict__ ctrl)
{
    const bool isf32 = sniff_f32(trans_raw);
    const int dir = (int)(blockIdx.x >> 5);
    const int wg  = (int)(blockIdx.x & 31);
    const int j0  = wg * 16;
    const unsigned salt = (unsigned)ctrl[4];
    const void* Whh = dir ? w_hh_b : w_hh_f;
    const float* xp = dir ? xp_b : xp_f;
    float* hs       = dir ? hs_b : hs_f;
    u64* ring       = dir ? ring_b : ring_f;

    const int tid = (int)threadIdx.x;
    const int rp  = tid >> 3;      // row-pair 0..31
    const int ks  = tid & 7;       // k-segment (64 wide)
    const int d   = rp >> 1;       // local dim 0..15
    const int gp  = rp & 1;        // 0 -> gates i,f ; 1 -> gates g,o
    const int g0r = gp * 2;

    __shared__ float h_lds[512 + 32];   // p(j) = j + ((j>>6)<<2)

    // 2 rows x 64 k of W_hh per lane (f32 in VGPRs; 128 total -> no spill)
    float wreg[2][64];
    #pragma unroll
    for (int rl = 0; rl < 2; ++rl) {
        const long roff = (long)((g0r + rl) * H_DIM + j0 + d) * H_DIM + ks * 64;
        if (isf32) {
            const float* wrow = (const float*)Whh + roff;
            #pragma unroll
            for (int b = 0; b < 16; ++b) *(float4*)&wreg[rl][b * 4] = *(const float4*)(wrow + b * 4);
        } else {
            const u16* wrow = (const u16*)Whh + roff;
            #pragma unroll
            for (int b = 0; b < 8; ++b) unpack8_bf16(wrow + b * 8, &wreg[rl][b * 8]);
        }
    }

    {   // init h_lds (w0 even: never straddles a 64-block)
        const int w0 = tid * 2;
        h_lds[w0 + ((w0 >> 6) << 2)]     = ldf(h0, dir * H_DIM + w0, isf32);
        h_lds[w0 + 1 + ((w0 >> 6) << 2)] = ldf(h0, dir * H_DIM + w0 + 1, isf32);
    }

    const bool is_act = ((tid & 15) == 0);   // ks==0 && gp==0: one per dim
    const int  jown   = j0 + d;
    float cst = 0.f;
    if (is_act) cst = ldf(c0, dir * H_DIM + jown, isf32);

    // poller mapping: 240 non-act lanes cover 496 remote words (2 or 3 each)
    const int b16 = tid >> 4, off = tid & 15;
    const int pidx = is_act ? -1 : (b16 * 15 + off - 1);   // 0..239
    int jw0 = 0, jw1 = 0, jw2 = -1;
    if (pidx >= 0) {
        const int w0 = 2 * pidx, w1 = 2 * pidx + 1;
        jw0 = w0 + (w0 >= j0 ? 16 : 0);
        jw1 = w1 + (w1 >= j0 ? 16 : 0);
        if (pidx < 16) { const int w2 = 480 + pidx; jw2 = w2 + (w2 >= j0 ? 16 : 0); }
    }

    int t = dir ? (L_SEQ - 1) : 0;
    float xc0 = 0, xc1 = 0, xc2 = 0, xc3 = 0, xn0 = 0, xn1 = 0, xn2 = 0, xn3 = 0;
    if (is_act) {
        const float* xr = xp + (long)t * G_DIM + jown;
        xn0 = xr[0]; xn1 = xr[H_DIM]; xn2 = xr[2 * H_DIM]; xn3 = xr[3 * H_DIM];
    }
    __syncthreads();

    #pragma unroll 1
    for (int k = 0; k < L_SEQ; ++k) {
        t = dir ? (L_SEQ - 1 - k) : k;
        const long rb = (long)(k & (RING_SLOTS - 1)) * H_DIM;
        const unsigned tagv = salt + (unsigned)(k + 1);

        if (is_act) {
            xc0 = xn0; xc1 = xn1; xc2 = xn2; xc3 = xn3;
            if (k + 1 < L_SEQ) {
                const int nt = dir ? (t - 1) : (t + 1);
                const float* xr = xp + (long)nt * G_DIM + jown;
                xn0 = xr[0]; xn1 = xr[H_DIM]; xn2 = xr[2 * H_DIM]; xn3 = xr[3 * H_DIM];
            }
        }

        // matvec: 2 rows x 64 k (16 ds_read_b128, conflict-free via 68-stride)
        float a0 = 0, a1 = 0;
        const float4* hb = (const float4*)(h_lds + ks * 68);
        #pragma unroll
        for (int q = 0; q < 16; ++q) {
            const float4 hv = hb[q];
            a0 = fmaf(wreg[0][4*q+0], hv.x, a0); a0 = fmaf(wreg[0][4*q+1], hv.y, a0);
            a0 = fmaf(wreg[0][4*q+2], hv.z, a0); a0 = fmaf(wreg[0][4*q+3], hv.w, a0);
            a1 = fmaf(wreg[1][4*q+0], hv.x, a1); a1 = fmaf(wreg[1][4*q+1], hv.y, a1);
            a1 = fmaf(wreg[1][4*q+2], hv.z, a1); a1 = fmaf(wreg[1][4*q+3], hv.w, a1);
        }
        // k-reduce across the 8 ks lanes (tid bits 0..2 -> in-wave)
        #pragma unroll
        for (int m = 1; m < 8; m <<= 1) { a0 += __shfl_xor(a0, m); a1 += __shfl_xor(a1, m); }
        // partner row-pair (tid bit 3): other two gates of the same dim
        const float b0 = __shfl_xor(a0, 8);
        const float b1 = __shfl_xor(a1, 8);

        if (is_act) {
            const float iv = fsig(a0 + xc0);     // gate i (row g=0)
            const float fo = fsig(a1 + xc1);     // gate f (row g=1)
            const float gv = ftanh(b0 + xc2);    // gate g (row g=2, partner)
            const float ov = fsig(b1 + xc3);     // gate o (row g=3, partner)
            cst = fo * cst + iv * gv;
            const float hv2 = ov * ftanh(cst);
            h_lds[jown + ((jown >> 6) << 2)] = hv2;
            hs[(long)t * H_DIM + jown] = hv2;                 // history for k_feats
            const u64 pk = (((u64)tagv) << 32) | (u64)__float_as_uint(hv2);
            // far-atomic publish: RMW executes at the device coherence point.
            atomicExch(&ring[rb + jown], pk);
        }

        if (k + 1 < L_SEQ && pidx >= 0) {
            u64* pa0 = &ring[rb + jw0];
            u64* pa1 = &ring[rb + jw1];
            u64* pa2 = (jw2 >= 0) ? &ring[rb + jw2] : pa0;
            u64 v0 = 0, v1 = 0, v2 = 0;
            bool q0 = false, q1 = false, q2 = (jw2 < 0);
            do {   // all missing words polled concurrently -> 1-latency retry period
                if (!q0) { v0 = __hip_atomic_load(pa0, __ATOMIC_RELAXED, __HIP_MEMORY_SCOPE_AGENT); }
                if (!q1) { v1 = __hip_atomic_load(pa1, __ATOMIC_RELAXED, __HIP_MEMORY_SCOPE_AGENT); }
                if (!q2) { v2 = __hip_atomic_load(pa2, __ATOMIC_RELAXED, __HIP_MEMORY_SCOPE_AGENT); }
                q0 = q0 || ((unsigned)(v0 >> 32) == tagv);
                q1 = q1 || ((unsigned)(v1 >> 32) == tagv);
                q2 = q2 || ((unsigned)(v2 >> 32) == tagv);
            } while (!(q0 && q1 && q2));
            h_lds[jw0 + ((jw0 >> 6) << 2)] = __uint_as_float((unsigned)v0);
            h_lds[jw1 + ((jw1 >> 6) << 2)] = __uint_as_float((unsigned)v1);
            if (jw2 >= 0) h_lds[jw2 + ((jw2 >> 6) << 2)] = __uint_as_float((unsigned)v2);
        }
        __syncthreads();
    }
}

// ---------------------------------------------------------------------------
// K3: feats[t][n] = hs_f[t]·w_out[n][:512] + hs_b[t]·w_out[n][512:] + b_out[n]
// ---------------------------------------------------------------------------
__global__ __launch_bounds__(256) void k_feats(
    const float* __restrict__ hs_f, const float* __restrict__ hs_b,
    const void* __restrict__ w_out, const void* __restrict__ b_out,
    const void* __restrict__ trans_raw, float* __restrict__ feats)
{
    const bool isf32 = sniff_f32(trans_raw);
    const int n  = (int)threadIdx.x & 31;
    const int tl = (int)threadIdx.x >> 5;
    const int t  = (int)blockIdx.x * 8 + tl;
    const float* hf = hs_f + (long)t * H_DIM;
    const float* hb = hs_b + (long)t * H_DIM;
    float acc = ldf(b_out, n, isf32);
    if (isf32) {
        const float* wf = (const float*)w_out + (long)n * 1024;
        const float* wb = wf + 512;
        #pragma unroll 4
        for (int j = 0; j < 512; j += 4) {
            const float4 hv = *(const float4*)&hf[j];
            const float4 wv = *(const float4*)&wf[j];
            acc = fmaf(hv.x, wv.x, acc); acc = fmaf(hv.y, wv.y, acc);
            acc = fmaf(hv.z, wv.z, acc); acc = fmaf(hv.w, wv.w, acc);
            const float4 hv2 = *(const float4*)&hb[j];
            const float4 wv2 = *(const float4*)&wb[j];
            acc = fmaf(hv2.x, wv2.x, acc); acc = fmaf(hv2.y, wv2.y, acc);
            acc = fmaf(hv2.z, wv2.z, acc); acc = fmaf(hv2.w, wv2.w, acc);
        }
    } else {
        const u16* wfh = (const u16*)w_out + (long)n * 1024;
        const u16* wbh = wfh + 512;
        #pragma unroll 2
        for (int j = 0; j < 512; j += 8) {
            float wt[8];
            unpack8_bf16(&wfh[j], wt);
            const float4 h0v = *(const float4*)&hf[j];
            const float4 h1v = *(const float4*)&hf[j + 4];
            acc = fmaf(h0v.x, wt[0], acc); acc = fmaf(h0v.y, wt[1], acc);
            acc = fmaf(h0v.z, wt[2], acc); acc = fmaf(h0v.w, wt[3], acc);
            acc = fmaf(h1v.x, wt[4], acc); acc = fmaf(h1v.y, wt[5], acc);
            acc = fmaf(h1v.z, wt[6], acc); acc = fmaf(h1v.w, wt[7], acc);
            unpack8_bf16(&wbh[j], wt);
            const float4 h2v = *(const float4*)&hb[j];
            const float4 h3v = *(const float4*)&hb[j + 4];
            acc = fmaf(h2v.x, wt[0], acc); acc = fmaf(h2v.y, wt[1], acc);
            acc = fmaf(h2v.z, wt[2], acc); acc = fmaf(h2v.w, wt[3], acc);
            acc = fmaf(h3v.x, wt[4], acc); acc = fmaf(h3v.y, wt[5], acc);
            acc = fmaf(h3v.z, wt[6], acc); acc = fmaf(h3v.w, wt[7], acc);
        }
    }
    feats[(long)t * 32 + n] = acc;
}

// ---------------------------------------------------------------------------
// K4: Viterbi forward — r7's proven structure (per-lane 16 candidates from
// LDS fv broadcast + ONE cross-half shuffle combine), with the 16-deep
// dependent compare chain replaced by a 4-level NAMED-SCALAR tree (no
// arrays beyond r7's proven tr[16]/fvv[16]; nothing runtime-indexable ->
// no scratch risk; r11's array-based tree spilled and cost 4x).
// Left-preferring >= tree == sequential first-max under strict >; max is
// bit-exact. Then chunked parallel backtrace (unchanged).
// Output (f32): out[0]=score, out[1..]=path.
// ---------------------------------------------------------------------------
__global__ __launch_bounds__(64) void k_viterbi(
    const float* __restrict__ feats, const void* __restrict__ trans_raw,
    u8* __restrict__ bptr, float* __restrict__ out)
{
    const bool isf32 = sniff_f32(trans_raw);
    const int lane = (int)threadIdx.x;
    const int n = lane & 31, half = lane >> 5;
    __shared__ __align__(16) float fv_l[32];
    __shared__ u8 mlds[64 * 32];
    __shared__ u8 entry[64];

    float tr[16];
    #pragma unroll
    for (int i = 0; i < 16; ++i) tr[i] = ldf(trans_raw, n * 32 + half * 16 + i, isf32);
    const float tr_end = ldf(trans_raw, 32 + n, isf32);   // trans[END=1][n]

    if (half == 0) fv_l[n] = (n == 0) ? 0.f : -10000.f;   // START=0
    float fvreg = 0.f;
    float fnext = feats[n];
    #pragma unroll 1
    for (int tt = 0; tt < L_SEQ; ++tt) {
        const float fcur = fnext;
        const int nt = (tt + 1 < L_SEQ) ? tt + 1 : tt;
        fnext = feats[(long)nt * 32 + n];

        // broadcast-read this lane's 16 fv values (4 x ds_read_b128, batched)
        float fvv[16];
        *(float4*)&fvv[0]  = *(const float4*)&fv_l[half * 16 + 0];
        *(float4*)&fvv[4]  = *(const float4*)&fv_l[half * 16 + 4];
        *(float4*)&fvv[8]  = *(const float4*)&fv_l[half * 16 + 8];
        *(float4*)&fvv[12] = *(const float4*)&fv_l[half * 16 + 12];

        // 4-level leftmost-max tree, all named scalars (spill-proof)
        const float c0  = tr[0]  + fvv[0],  c1  = tr[1]  + fvv[1];
        const float c2  = tr[2]  + fvv[2],  c3  = tr[3]  + fvv[3];
        const float c4  = tr[4]  + fvv[4],  c5  = tr[5]  + fvv[5];
        const float c6  = tr[6]  + fvv[6],  c7  = tr[7]  + fvv[7];
        const float c8  = tr[8]  + fvv[8],  c9  = tr[9]  + fvv[9];
        const float c10 = tr[10] + fvv[10], c11 = tr[11] + fvv[11];
        const float c12 = tr[12] + fvv[12], c13 = tr[13] + fvv[13];
        const float c14 = tr[14] + fvv[14], c15 = tr[15] + fvv[15];

        const bool p0 = (c0  >= c1);  const float v0 = p0 ? c0  : c1;  const int x0 = p0 ? 0  : 1;
        const bool p1 = (c2  >= c3);  const float v1 = p1 ? c2  : c3;  const int x1 = p1 ? 2  : 3;
        const bool p2 = (c4  >= c5);  const float v2 = p2 ? c4  : c5;  const int x2 = p2 ? 4  : 5;
        const bool p3 = (c6  >= c7);  const float v3 = p3 ? c6  : c7;  const int x3 = p3 ? 6  : 7;
        const bool p4 = (c8  >= c9);  const float v4 = p4 ? c8  : c9;  const int x4 = p4 ? 8  : 9;
        const bool p5 = (c10 >= c11); const float v5 = p5 ? c10 : c11; const int x5 = p5 ? 10 : 11;
        const bool p6 = (c12 >= c13); const float v6 = p6 ? c12 : c13; const int x6 = p6 ? 12 : 13;
        const bool p7 = (c14 >= c15); const float v7 = p7 ? c14 : c15; const int x7 = p7 ? 14 : 15;

        const bool q0 = (v0 >= v1); const float u0 = q0 ? v0 : v1; const int y0 = q0 ? x0 : x1;
        const bool q1 = (v2 >= v3); const float u1 = q1 ? v2 : v3; const int y1 = q1 ? x2 : x3;
        const bool q2 = (v4 >= v5); const float u2 = q2 ? v4 : v5; const int y2 = q2 ? x4 : x5;
        const bool q3 = (v6 >= v7); const float u3 = q3 ? v6 : v7; const int y3 = q3 ? x6 : x7;

        const bool r0 = (u0 >= u1); const float w0 = r0 ? u0 : u1; const int z0 = r0 ? y0 : y1;
        const bool r1 = (u2 >= u3); const float w1 = r1 ? u2 : u3; const int z1 = r1 ? y2 : y3;

        const bool rf = (w0 >= w1);
        float best = rf ? w0 : w1;
        int   bp   = half * 16 + (rf ? z0 : z1);

        // cross-half combine (one independent shuffle pair)
        const float ob = __shfl_xor(best, 32);
        const int  obp = __shfl_xor(bp, 32);
        if (ob > best || (ob == best && obp < bp)) { best = ob; bp = obp; }

        fvreg = best + fcur;                   // all lanes identical per n
        if (half == 0) {
            bptr[(long)tt * 32 + n] = (u8)bp;
            fv_l[n] = fvreg;                   // publish fv(t+1); in-wave, in-order LDS
        }
    }

    float term = (half == 0) ? (fvreg + tr_end) : -3.4e38f;
    int   ti   = (half == 0) ? n : 1000;
    #pragma unroll
    for (int m = 1; m < 64; m <<= 1) {
        const float ov = __shfl_xor(term, m);
        const int   oi = __shfl_xor(ti, m);
        if (ov > term || (ov == term && oi < ti)) { term = ov; ti = oi; }
    }
    if (lane == 0) out[0] = term;
    __syncthreads();

    unsigned cur[32];
    #pragma unroll
    for (int ch = 0; ch < 32; ++ch) cur[ch] = (unsigned)ch;
    const int cbase = lane * 64;
    for (int s = 63; s >= 0; --s) {
        const u8* row = bptr + (long)(cbase + s) * 32;
        #pragma unroll
        for (int ch = 0; ch < 32; ++ch) cur[ch] = row[cur[ch]];
    }
    #pragma unroll
    for (int ch = 0; ch < 32; ++ch) mlds[lane * 32 + ch] = (u8)cur[ch];
    __syncthreads();

    if (lane == 0) {
        int tag = ti;
        for (int c = 63; c >= 0; --c) { entry[c] = (u8)tag; tag = mlds[c * 32 + tag]; }
    }
    __syncthreads();

    {
        int tag = entry[lane];
        for (int s = 63; s >= 0; --s) {
            const int gidx = cbase + s;
            out[1 + gidx] = (float)tag;
            tag = bptr[(long)gidx * 32 + tag];
        }
    }
}

// ---------------------------------------------------------------------------
extern "C" void kernel_launch(void* const* d_in, const int* in_sizes, int n_in,
                              void* d_out, int out_size, void* d_ws, size_t ws_size,
                              hipStream_t stream)
{
    (void)in_sizes; (void)n_in; (void)out_size; (void)ws_size;
    const int* sent  = (const int*)d_in[0];
    const void* embed  = d_in[1];
    const void* w_ih_f = d_in[2];
    const void* w_hh_f = d_in[3];
    const void* b_ih_f = d_in[4];
    const void* b_hh_f = d_in[5];
    const void* w_ih_b = d_in[6];
    const void* w_hh_b = d_in[7];
    const void* b_ih_b = d_in[8];
    const void* b_hh_b = d_in[9];
    const void* w_out  = d_in[10];
    const void* b_out  = d_in[11];
    const void* h0     = d_in[12];
    const void* c0     = d_in[13];
    const void* trans  = d_in[14];

    // Layout: 80.2 MB total, within the baseline's proven 96 MB footprint.
    char* ws = (char*)d_ws;
    float* xp_f  = (float*)(ws);                              // 32 MB
    float* xp_b  = (float*)(ws + (32ull << 20));              // 32 MB
    float* hs_f  = (float*)(ws + (64ull << 20));              //  8 MB (4096x512 f32)
    float* hs_b  = (float*)(ws + (72ull << 20));              //  8 MB
    u64*   ring_f = (u64*)(ws + (80ull << 20));               // 16 KB (4x512 u64)
    u64*   ring_b = (u64*)(ws + (80ull << 20) + (64u << 10)); // 16 KB
    int*   ctrl   = (int*)(ws + (80ull << 20) + (128u << 10));// 32 B (salt)
    float* feats = (float*)(ws);                              // reuses xp_f (dead)
    u8*    bptr  = (u8*)(ws + (1ull << 20));                  // 128 KB, dead region

    k_xproj<<<dim3(128, 2), 256, 0, stream>>>(sent, embed,
        w_ih_f, b_ih_f, b_hh_f, w_ih_b, b_ih_b, b_hh_b, trans, xp_f, xp_b, ctrl);
    k_lstm<<<64, 256, 0, stream>>>(w_hh_f, w_hh_b, h0, c0, trans, xp_f, xp_b,
                                   hs_f, hs_b, ring_f, ring_b, ctrl);
    k_feats<<<512, 256, 0, stream>>>(hs_f, hs_b, w_out, b_out, trans, feats);
    k_viterbi<<<1, 64, 0, stream>>>(feats, trans, bptr, (float*)d_out);
}